// Round 5
// baseline (318.623 us; speedup 1.0000x reference)
//
#include <hip/hip_runtime.h>
#include <math.h>

typedef __attribute__((ext_vector_type(8))) short short8;
typedef __attribute__((ext_vector_type(4))) float f32x4;
#define MFMA __builtin_amdgcn_mfma_f32_16x16x32_bf16

#define BN_EPS 1e-5f

// ---------------- workspace layout (float offsets) ----------------
// w1c2: 2048 u16   [n2][ol16][kc4][p2][e8]
// w2c2: 36864 u16  [tap9][n4][ol16][kc4][p2][e8]
// w3c2: 147456 u16 [tap9][s2][nf8][ol16][kc4][p2][e8]
static const size_t W1C2_OFF = 0;
static const size_t W2C2_OFF = 1024;
static const size_t W3C2_OFF = 19456;
static const size_t B1_OFF   = 93184;
static const size_t B2_OFF   = 93216;
static const size_t B3_OFF   = 93280;

__device__ inline unsigned short rneb(float x) {
    unsigned u = __float_as_uint(x);
    return (unsigned short)((u + 0x7FFFu + ((u >> 16) & 1u)) >> 16);
}
__device__ inline float b2f(unsigned short h) {
    return __uint_as_float(((unsigned)h) << 16);
}

// ---------------- prep: BN-fold + reorder to MFMA B-fragment layout, hi/lo split
__global__ __launch_bounds__(256) void k_prep(
    const float* __restrict__ c1w, const float* __restrict__ c2w, const float* __restrict__ c3w,
    const float* __restrict__ c1b, const float* __restrict__ g1, const float* __restrict__ be1,
    const float* __restrict__ m1, const float* __restrict__ v1,
    const float* __restrict__ c2b, const float* __restrict__ g2, const float* __restrict__ be2,
    const float* __restrict__ m2, const float* __restrict__ v2,
    const float* __restrict__ c3b, const float* __restrict__ g3, const float* __restrict__ be3,
    const float* __restrict__ m3, const float* __restrict__ v3,
    unsigned short* __restrict__ w1c2, unsigned short* __restrict__ w2c2,
    unsigned short* __restrict__ w3c2,
    float* __restrict__ b1c, float* __restrict__ b2c, float* __restrict__ b3c)
{
    int i = blockIdx.x * 256 + threadIdx.x;
    if (i < 2048) {
        int e = i & 7, p = (i >> 3) & 1, kc = (i >> 4) & 3, ol = (i >> 6) & 15, n = i >> 10;
        int o = n * 16 + ol, k = kc * 8 + e;
        float s = g1[o] * rsqrtf(v1[o] + BN_EPS);
        float wv = (k < 27) ? c1w[o * 27 + k] * s : 0.f;
        unsigned short h = rneb(wv);
        w1c2[i] = p ? rneb(wv - b2f(h)) : h;
        return;
    }
    i -= 2048;
    if (i < 36864) {
        int e = i & 7, p = (i >> 3) & 1, kc = (i >> 4) & 3, ol = (i >> 6) & 15;
        int n = (i >> 10) & 3, tap = i >> 12;
        int o = n * 16 + ol, ci = kc * 8 + e;
        float s = g2[o] * rsqrtf(v2[o] + BN_EPS);
        float wv = c2w[o * 288 + ci * 9 + tap] * s;
        unsigned short h = rneb(wv);
        w2c2[i] = p ? rneb(wv - b2f(h)) : h;
        return;
    }
    i -= 36864;
    if (i < 147456) {
        int e = i & 7, p = (i >> 3) & 1, kc = (i >> 4) & 3, ol = (i >> 6) & 15;
        int nf = (i >> 10) & 7, s_ = (i >> 13) & 1, tap = i >> 14;
        int o = nf * 16 + ol, ci = s_ * 32 + kc * 8 + e;
        float sc = g3[o] * rsqrtf(v3[o] + BN_EPS);
        float wv = c3w[o * 576 + ci * 9 + tap] * sc;
        unsigned short h = rneb(wv);
        w3c2[i] = p ? rneb(wv - b2f(h)) : h;
        return;
    }
    i -= 147456;
    if (i < 32) { float s = g1[i]*rsqrtf(v1[i]+BN_EPS); b1c[i] = (c1b[i]-m1[i])*s + be1[i]; return; }
    i -= 32;
    if (i < 64) { float s = g2[i]*rsqrtf(v2[i]+BN_EPS); b2c[i] = (c2b[i]-m2[i])*s + be2[i]; return; }
    i -= 64;
    if (i < 128) { float s = g3[i]*rsqrtf(v3[i]+BN_EPS); b3c[i] = (c3b[i]-m3[i])*s + be3[i]; return; }
}

// ---------------- fully fused, 1 image/block, 512 thr, 3 blocks/CU ----------
// R1  (20736 u16 = 41472B): conv2 input [py18][kc4][px18][e8], hi 0 / lo +10368
//                           reused as conv3 input [py10][kc8][px11][e8], hi 0 / lo +7040
// R2x (3074 u32 = 12296B):  x packed (hi<<16|lo) per pixel, [3][32][32], no halo;
//                           [3072] = OOB zero slot. Reused after P1 for sFeat/sOut/sPart.
__global__ __launch_bounds__(512, 6) void k_fused(
    const float* __restrict__ x,
    const unsigned short* __restrict__ w1c2,
    const unsigned short* __restrict__ w2c2,
    const unsigned short* __restrict__ w3c2,
    const float* __restrict__ b1c, const float* __restrict__ b2c, const float* __restrict__ b3c,
    const float* __restrict__ w1e, const float* __restrict__ b1e,
    const float* __restrict__ w2e, const float* __restrict__ b2e,
    const float* __restrict__ gw, const float* __restrict__ gb,
    float* __restrict__ out)
{
    __shared__ __align__(16) unsigned short R1[20736];
    __shared__ __align__(16) unsigned int   R2x[3074];
    float* sFeat = (float*)R2x;          // [128], written in P3 (R2x dead after P1)
    float* sOutB = (float*)R2x + 128;    // [20]
    float* sPart = (float*)R2x + 160;    // [8][64]

    const int b = blockIdx.x, t = threadIdx.x;
    const int lane = t & 63, w = t >> 6;
    const int l15 = lane & 15, lg = lane >> 4;
    const int4 z4 = {0, 0, 0, 0};

    // ---------------- P0: stage packed x; conv2-in halo zeros ----------------
    {
        const float* xb = x + (size_t)b * 3072;
        for (int i = t; i < 3072; i += 512) {
            float v = xb[i];
            unsigned short h = rneb(v);
            unsigned short lo = rneb(v - b2f(h));
            R2x[i] = ((unsigned)h << 16) | lo;
        }
        if (t == 0) R2x[3072] = 0;
        for (int hh = t; hh < 272; hh += 512) {      // 68 halo (py,px) x 4 kc
            int pr = hh >> 2, kc = hh & 3;
            int py, px;
            if (pr < 36) { py = (pr < 18) ? 0 : 17; px = (pr < 18) ? pr : pr - 18; }
            else { int r = pr - 36; py = 1 + (r >> 1); px = (r & 1) ? 17 : 0; }
            int ei = ((py * 4 + kc) * 18 + px) * 8;
            *(int4*)(R1 + ei) = z4;
            *(int4*)(R1 + 10368 + ei) = z4;
        }
    }
    __syncthreads();

    // ---------------- P1: conv1 (3->32 @32x32), relu+pool -> conv2 input -----
    {
        short8 b1h[2], b1l[2];
#pragma unroll
        for (int n = 0; n < 2; n++) {
            const short8* bp = (const short8*)(w1c2 + 16 * ((n * 16 + l15) * 4 + lg));
            b1h[n] = bp[0]; b1l[n] = bp[1];
        }
        int dyE[8], dxE[8], cbE[8];
#pragma unroll
        for (int e = 0; e < 8; e++) {
            int k = lg * 8 + e;
            if (k < 27) { int ci = k / 9, tp = k - ci * 9;
                          dyE[e] = tp / 3 - 1; dxE[e] = tp % 3 - 1; cbE[e] = ci << 10; }
            else { dyE[e] = -1000; dxE[e] = 0; cbE[e] = 0; }
        }
        float bia[2] = { b1c[l15], b1c[16 + l15] };
#pragma unroll 1
        for (int q = 0; q < 2; q++) {
            int m0 = 8 * w + 4 * q;
            f32x4 acc[4][2];
#pragma unroll
            for (int mi = 0; mi < 4; mi++)
#pragma unroll
                for (int n = 0; n < 2; n++) acc[mi][n] = (f32x4)0.f;
#pragma unroll
            for (int mi = 0; mi < 4; mi++) {
                int pos = 16 * (m0 + mi) + l15, py = pos >> 5, px = pos & 31;
                short8 ah, al;
#pragma unroll
                for (int e = 0; e < 8; e++) {
                    int yy = py + dyE[e], xv = px + dxE[e];
                    int idx = cbE[e] + (yy << 5) + xv;
                    bool ok = ((unsigned)yy < 32u) && ((unsigned)xv < 32u);
                    unsigned u = R2x[ok ? idx : 3072];
                    ah[e] = (short)(u >> 16);
                    al[e] = (short)(u & 0xFFFFu);
                }
#pragma unroll
                for (int n = 0; n < 2; n++) {
                    acc[mi][n] = MFMA(ah, b1h[n], acc[mi][n], 0, 0, 0);
                    acc[mi][n] = MFMA(ah, b1l[n], acc[mi][n], 0, 0, 0);
                    acc[mi][n] = MFMA(al, b1h[n], acc[mi][n], 0, 0, 0);
                }
            }
            int PY = 2 * w + q;
#pragma unroll
            for (int n = 0; n < 2; n++) {
                int o = n * 16 + l15;
#pragma unroll
                for (int h = 0; h < 2; h++)
#pragma unroll
                for (int jp = 0; jp < 2; jp++) {
                    float v00 = fmaxf(acc[h][n][2*jp]     + bia[n], 0.f);
                    float v01 = fmaxf(acc[h][n][2*jp + 1] + bia[n], 0.f);
                    float v10 = fmaxf(acc[h+2][n][2*jp]     + bia[n], 0.f);
                    float v11 = fmaxf(acc[h+2][n][2*jp + 1] + bia[n], 0.f);
                    float pm = fmaxf(fmaxf(v00, v01), fmaxf(v10, v11));
                    int PX = h * 8 + lg * 2 + jp;
                    unsigned short ph = rneb(pm), pl = rneb(pm - b2f(ph));
                    int ei = (((PY + 1) * 4 + (o >> 3)) * 18 + (PX + 1)) * 8 + (o & 7);
                    R1[ei] = ph; R1[10368 + ei] = pl;
                }
            }
        }
    }
    __syncthreads();

    // ---------------- P2: conv2 (32->64 @16x16), N-split waves + B prefetch ---
    {
        const int mh = w & 1, nn = w >> 1;
        f32x4 acc2[8];
#pragma unroll
        for (int mi = 0; mi < 8; mi++) acc2[mi] = (f32x4)0.f;
        const unsigned short* wb = w2c2 + ((size_t)(nn * 16 + l15) * 4 + lg) * 16;
        const int abase = (mh * 8) * 576 + lg * 144 + l15 * 8;
        short8 bhA, blA, bhB, blB;
#define LDB2(tp, BH, BL) { const short8* bp = (const short8*)(wb + (tp) * 4096); BH = bp[0]; BL = bp[1]; }
#define CMP2(tp, BH, BL) { int dy_ = (tp) / 3, dx_ = (tp) - 3 * dy_; \
        int roff_ = dy_ * 576 + dx_ * 8; \
        _Pragma("unroll") for (int mi = 0; mi < 8; mi++) { \
            int ea_ = abase + mi * 576 + roff_; \
            short8 ah_ = *(const short8*)(R1 + ea_); \
            short8 al_ = *(const short8*)(R1 + 10368 + ea_); \
            acc2[mi] = MFMA(ah_, BH, acc2[mi], 0, 0, 0); \
            acc2[mi] = MFMA(ah_, BL, acc2[mi], 0, 0, 0); \
            acc2[mi] = MFMA(al_, BH, acc2[mi], 0, 0, 0); } }
        LDB2(0, bhA, blA);
#pragma unroll 1
        for (int tp = 0; tp < 8; tp += 2) {
            LDB2(tp + 1, bhB, blB);
            CMP2(tp, bhA, blA);
            LDB2(tp + 2, bhA, blA);
            CMP2(tp + 1, bhB, blB);
        }
        CMP2(8, bhA, blA);
        __syncthreads();                            // conv2 reads of R1 done
        // epilogue: conv3-in halo zeros + relu+pool payload [py10][kc8][px11][e8]
        for (int hh = t; hh < 288; hh += 512) {     // 36 halo (py,px) x 8 kc
            int pr = hh >> 3, kc = hh & 7;
            int py, px;
            if (pr < 20) { py = (pr < 10) ? 0 : 9; px = (pr < 10) ? pr : pr - 10; }
            else { int r = pr - 20; py = 1 + (r >> 1); px = (r & 1) ? 9 : 0; }
            int ei = ((py * 8 + kc) * 11 + px) * 8;
            *(int4*)(R1 + ei) = z4;
            *(int4*)(R1 + 7040 + ei) = z4;
        }
        {
            int o = nn * 16 + l15;
            float bia = b2c[o];
#pragma unroll
            for (int mi2 = 0; mi2 < 4; mi2++) {
                int PY = mh * 4 + mi2;
#pragma unroll
                for (int jp = 0; jp < 2; jp++) {
                    float v00 = fmaxf(acc2[2*mi2][2*jp]     + bia, 0.f);
                    float v01 = fmaxf(acc2[2*mi2][2*jp + 1] + bia, 0.f);
                    float v10 = fmaxf(acc2[2*mi2+1][2*jp]     + bia, 0.f);
                    float v11 = fmaxf(acc2[2*mi2+1][2*jp + 1] + bia, 0.f);
                    float pm = fmaxf(fmaxf(v00, v01), fmaxf(v10, v11));
                    int PX = lg * 2 + jp;
                    unsigned short ph = rneb(pm), pl = rneb(pm - b2f(ph));
                    int ei = (((PY + 1) * 8 + (o >> 3)) * 11 + (PX + 1)) * 8 + (o & 7);
                    R1[ei] = ph; R1[7040 + ei] = pl;
                }
            }
        }
    }
    __syncthreads();

    // ---------------- P3: conv3 (64->128 @8x8), wave-per-nf + B prefetch ------
    {
        const int nf = w;
        f32x4 acc3[4];
#pragma unroll
        for (int mi = 0; mi < 4; mi++) acc3[mi] = (f32x4)0.f;
        const unsigned short* wb3 = w3c2 + ((size_t)(nf * 16 + l15) * 4 + lg) * 16;
        const int py0 = (l15 >> 3), px3 = l15 & 7;
        short8 bhA, blA, bhB, blB;
#define LDB3(ii, BH, BL) { const short8* bp = (const short8*)(wb3 + (ii) * 8192); BH = bp[0]; BL = bp[1]; }
#define CMP3(ii, BH, BL) { int tap_ = (ii) >> 1, s_ = (ii) & 1; \
        int dy_ = tap_ / 3, dx_ = tap_ - 3 * dy_; \
        int roff_ = dy_ * 704 + (s_ * 4 + lg) * 88 + dx_ * 8 + px3 * 8; \
        _Pragma("unroll") for (int mi = 0; mi < 4; mi++) { \
            int ea_ = (mi * 2 + py0) * 704 + roff_; \
            short8 ah_ = *(const short8*)(R1 + ea_); \
            short8 al_ = *(const short8*)(R1 + 7040 + ea_); \
            acc3[mi] = MFMA(ah_, BH, acc3[mi], 0, 0, 0); \
            acc3[mi] = MFMA(ah_, BL, acc3[mi], 0, 0, 0); \
            acc3[mi] = MFMA(al_, BH, acc3[mi], 0, 0, 0); } }
        LDB3(0, bhA, blA);
#pragma unroll 1
        for (int ii = 0; ii < 16; ii += 2) {
            LDB3(ii + 1, bhB, blB);
            CMP3(ii, bhA, blA);
            LDB3(ii + 2, bhA, blA);
            CMP3(ii + 1, bhB, blB);
        }
        LDB3(17, bhB, blB);
        CMP3(16, bhA, blA);
        CMP3(17, bhB, blB);
        // epilogue: relu + 2x2 maxpool + avg -> sFeat
        {
            int o = nf * 16 + l15;
            float bia = b3c[o];
            float featsum = 0.f;
#pragma unroll
            for (int mi = 0; mi < 4; mi++) {
                float sumv = 0.f;
#pragma unroll
                for (int jp = 0; jp < 2; jp++) {
                    float v0 = fmaxf(acc3[mi][2*jp]     + bia, 0.f);
                    float v1 = fmaxf(acc3[mi][2*jp + 1] + bia, 0.f);
                    float vm = fmaxf(v0, v1);
                    vm = fmaxf(vm, __shfl_xor(vm, 32, 64));   // py-pair
                    sumv += vm;
                }
                sumv += __shfl_xor(sumv, 16, 64);             // px halves
                featsum += sumv;
            }
            if (lane < 16) sFeat[nf * 16 + lane] = featsum * (1.0f / 16.0f);
        }
    }
    __syncthreads();

    // ---------------- P4: gate top-2 (all waves) + split expert MLPs ----------
    int i1 = 0, i2 = 0;
    float wk1 = 0.f, wk2 = 0.f;
    {
        float f0 = sFeat[lane], f1 = sFeat[64 + lane];
        float lgt[8];
#pragma unroll
        for (int e = 0; e < 8; e++) {
            float p = f0 * gw[lane * 8 + e] + f1 * gw[(64 + lane) * 8 + e];
#pragma unroll
            for (int s = 1; s < 64; s <<= 1) p += __shfl_xor(p, s, 64);
            lgt[e] = p + gb[e];
        }
        float v1m = -1e30f, v2m = -1e30f;
#pragma unroll
        for (int e = 0; e < 8; e++) {
            float le = lgt[e];
            if (le > v1m) { v2m = v1m; i2 = i1; v1m = le; i1 = e; }
            else if (le > v2m) { v2m = le; i2 = e; }
        }
        float ex = expf(v2m - v1m);
        wk1 = 1.f / (1.f + ex); wk2 = ex / (1.f + ex);
        // wave w: expert (w<4 ? i1 : i2), k-chunk (w&3)*32
        int e = (w < 4) ? i1 : i2;
        int k0 = (w & 3) * 32;
        const float* W1 = w1e + (size_t)e * 8192 + (size_t)k0 * 64;
        float hj = 0.f;
#pragma unroll 8
        for (int kk = 0; kk < 32; kk++) hj += sFeat[k0 + kk] * W1[kk * 64 + lane];
        sPart[w * 64 + lane] = hj;
    }
    __syncthreads();
    if (w < 2) {
        int e = (w == 0) ? i1 : i2;
        float wk = (w == 0) ? wk1 : wk2;
        float hj = b1e[e * 64 + lane]
                 + sPart[(w * 4 + 0) * 64 + lane] + sPart[(w * 4 + 1) * 64 + lane]
                 + sPart[(w * 4 + 2) * 64 + lane] + sPart[(w * 4 + 3) * 64 + lane];
        hj = fmaxf(hj, 0.f);
        const float* W2 = w2e + (size_t)e * 640 + lane * 10;
#pragma unroll
        for (int o = 0; o < 10; o++) {
            float po = hj * W2[o];
#pragma unroll
            for (int s = 1; s < 64; s <<= 1) po += __shfl_xor(po, s, 64);
            if (lane == 0) sOutB[w * 10 + o] = wk * (po + b2e[e * 10 + o]);
        }
    }
    __syncthreads();
    if (t < 10) out[(size_t)b * 10 + t] = sOutB[t] + sOutB[10 + t];
}

extern "C" void kernel_launch(void* const* d_in, const int* in_sizes, int n_in,
                              void* d_out, int out_size, void* d_ws, size_t ws_size,
                              hipStream_t stream)
{
    const float* x   = (const float*)d_in[0];
    const float* c1w = (const float*)d_in[1];
    const float* c1b = (const float*)d_in[2];
    const float* g1  = (const float*)d_in[3];
    const float* be1 = (const float*)d_in[4];
    const float* m1  = (const float*)d_in[5];
    const float* v1  = (const float*)d_in[6];
    const float* c2w = (const float*)d_in[7];
    const float* c2b = (const float*)d_in[8];
    const float* g2  = (const float*)d_in[9];
    const float* be2 = (const float*)d_in[10];
    const float* m2  = (const float*)d_in[11];
    const float* v2  = (const float*)d_in[12];
    const float* c3w = (const float*)d_in[13];
    const float* c3b = (const float*)d_in[14];
    const float* g3  = (const float*)d_in[15];
    const float* be3 = (const float*)d_in[16];
    const float* m3  = (const float*)d_in[17];
    const float* v3  = (const float*)d_in[18];
    const float* w1e = (const float*)d_in[19];
    const float* b1e = (const float*)d_in[20];
    const float* w2e = (const float*)d_in[21];
    const float* b2e = (const float*)d_in[22];
    const float* gw  = (const float*)d_in[23];
    const float* gb  = (const float*)d_in[24];

    float* ws = (float*)d_ws;
    unsigned short* w1c2 = (unsigned short*)(ws + W1C2_OFF);
    unsigned short* w2c2 = (unsigned short*)(ws + W2C2_OFF);
    unsigned short* w3c2 = (unsigned short*)(ws + W3C2_OFF);
    float* b1c = ws + B1_OFF;
    float* b2c = ws + B2_OFF;
    float* b3c = ws + B3_OFF;

    k_prep<<<729, 256, 0, stream>>>(c1w, c2w, c3w,
                                    c1b, g1, be1, m1, v1,
                                    c2b, g2, be2, m2, v2,
                                    c3b, g3, be3, m3, v3,
                                    w1c2, w2c2, w3c2, b1c, b2c, b3c);
    k_fused<<<4096, 512, 0, stream>>>(x, w1c2, w2c2, w3c2, b1c, b2c, b3c,
                                      w1e, b1e, w2e, b2e, gw, gb, (float*)d_out);
}

// Round 6
// 295.150 us; speedup vs baseline: 1.0795x; 1.0795x over previous
//
#include <hip/hip_runtime.h>
#include <math.h>

typedef __attribute__((ext_vector_type(8))) short short8;
typedef __attribute__((ext_vector_type(4))) float f32x4;
#define MFMA __builtin_amdgcn_mfma_f32_16x16x32_bf16

#define BN_EPS 1e-5f

// ---------------- workspace layout (float offsets) ----------------
// w1c2: 2048 u16   [n2][ol16][kc4][p2][e8]
// w2c2: 36864 u16  [tap9][n4][ol16][kc4][p2][e8]
// w3c2: 147456 u16 [tap9][s2][nf8][ol16][kc4][p2][e8]
static const size_t W1C2_OFF = 0;
static const size_t W2C2_OFF = 1024;
static const size_t W3C2_OFF = 19456;
static const size_t B1_OFF   = 93184;
static const size_t B2_OFF   = 93216;
static const size_t B3_OFF   = 93280;

__device__ inline unsigned short rneb(float x) {
    unsigned u = __float_as_uint(x);
    return (unsigned short)((u + 0x7FFFu + ((u >> 16) & 1u)) >> 16);
}
__device__ inline float b2f(unsigned short h) {
    return __uint_as_float(((unsigned)h) << 16);
}

// ---------------- prep: BN-fold + reorder to MFMA B-fragment layout, hi/lo split
__global__ __launch_bounds__(256) void k_prep(
    const float* __restrict__ c1w, const float* __restrict__ c2w, const float* __restrict__ c3w,
    const float* __restrict__ c1b, const float* __restrict__ g1, const float* __restrict__ be1,
    const float* __restrict__ m1, const float* __restrict__ v1,
    const float* __restrict__ c2b, const float* __restrict__ g2, const float* __restrict__ be2,
    const float* __restrict__ m2, const float* __restrict__ v2,
    const float* __restrict__ c3b, const float* __restrict__ g3, const float* __restrict__ be3,
    const float* __restrict__ m3, const float* __restrict__ v3,
    unsigned short* __restrict__ w1c2, unsigned short* __restrict__ w2c2,
    unsigned short* __restrict__ w3c2,
    float* __restrict__ b1c, float* __restrict__ b2c, float* __restrict__ b3c)
{
    int i = blockIdx.x * 256 + threadIdx.x;
    if (i < 2048) {
        int e = i & 7, p = (i >> 3) & 1, kc = (i >> 4) & 3, ol = (i >> 6) & 15, n = i >> 10;
        int o = n * 16 + ol, k = kc * 8 + e;
        float s = g1[o] * rsqrtf(v1[o] + BN_EPS);
        float wv = (k < 27) ? c1w[o * 27 + k] * s : 0.f;
        unsigned short h = rneb(wv);
        w1c2[i] = p ? rneb(wv - b2f(h)) : h;
        return;
    }
    i -= 2048;
    if (i < 36864) {
        int e = i & 7, p = (i >> 3) & 1, kc = (i >> 4) & 3, ol = (i >> 6) & 15;
        int n = (i >> 10) & 3, tap = i >> 12;
        int o = n * 16 + ol, ci = kc * 8 + e;
        float s = g2[o] * rsqrtf(v2[o] + BN_EPS);
        float wv = c2w[o * 288 + ci * 9 + tap] * s;
        unsigned short h = rneb(wv);
        w2c2[i] = p ? rneb(wv - b2f(h)) : h;
        return;
    }
    i -= 36864;
    if (i < 147456) {
        int e = i & 7, p = (i >> 3) & 1, kc = (i >> 4) & 3, ol = (i >> 6) & 15;
        int nf = (i >> 10) & 7, s_ = (i >> 13) & 1, tap = i >> 14;
        int o = nf * 16 + ol, ci = s_ * 32 + kc * 8 + e;
        float sc = g3[o] * rsqrtf(v3[o] + BN_EPS);
        float wv = c3w[o * 576 + ci * 9 + tap] * sc;
        unsigned short h = rneb(wv);
        w3c2[i] = p ? rneb(wv - b2f(h)) : h;
        return;
    }
    i -= 147456;
    if (i < 32) { float s = g1[i]*rsqrtf(v1[i]+BN_EPS); b1c[i] = (c1b[i]-m1[i])*s + be1[i]; return; }
    i -= 32;
    if (i < 64) { float s = g2[i]*rsqrtf(v2[i]+BN_EPS); b2c[i] = (c2b[i]-m2[i])*s + be2[i]; return; }
    i -= 64;
    if (i < 128) { float s = g3[i]*rsqrtf(v3[i]+BN_EPS); b3c[i] = (c3b[i]-m3[i])*s + be3[i]; return; }
}

// ---------------- fully fused, 1 image/block, 512 thr ----------------
// R1  (20736 u16 = 41472B): conv2 input [py18][kc4][px18][e8], hi 0 / lo +10368
//                           reused as conv3 input [py10][kc8][px11][e8], hi 0 / lo +7040
// R2x (3074 u32 = 12296B):  x packed (hi<<16|lo) per pixel, [3][32][32], no halo;
//                           [3072] = OOB zero slot. Reused after P1 for sFeat/sOut/sPart.
// LDS total 54272B -> 3 blocks/CU possible; launch_bounds(512,4) keeps the
// round-4 no-spill codegen (64 VGPR) -- do NOT tighten to 6 (spilled, R5).
__global__ __launch_bounds__(512, 4) void k_fused(
    const float* __restrict__ x,
    const unsigned short* __restrict__ w1c2,
    const unsigned short* __restrict__ w2c2,
    const unsigned short* __restrict__ w3c2,
    const float* __restrict__ b1c, const float* __restrict__ b2c, const float* __restrict__ b3c,
    const float* __restrict__ w1e, const float* __restrict__ b1e,
    const float* __restrict__ w2e, const float* __restrict__ b2e,
    const float* __restrict__ gw, const float* __restrict__ gb,
    float* __restrict__ out)
{
    __shared__ __align__(16) unsigned short R1[20736];
    __shared__ __align__(16) unsigned int   R2x[3074];
    float* sFeat = (float*)R2x;          // [128], written in P3 (R2x dead after P1)
    float* sOutB = (float*)R2x + 128;    // [20]
    float* sPart = (float*)R2x + 160;    // [8][64]

    const int b = blockIdx.x, t = threadIdx.x;
    const int lane = t & 63, w = t >> 6;
    const int l15 = lane & 15, lg = lane >> 4;
    const int4 z4 = {0, 0, 0, 0};

    // ---------------- P0: stage packed x; conv2-in halo zeros ----------------
    {
        const float* xb = x + (size_t)b * 3072;
        for (int i = t; i < 3072; i += 512) {
            float v = xb[i];
            unsigned short h = rneb(v);
            unsigned short lo = rneb(v - b2f(h));
            R2x[i] = ((unsigned)h << 16) | lo;
        }
        if (t == 0) R2x[3072] = 0;
        for (int hh = t; hh < 272; hh += 512) {      // 68 halo (py,px) x 4 kc
            int pr = hh >> 2, kc = hh & 3;
            int py, px;
            if (pr < 36) { py = (pr < 18) ? 0 : 17; px = (pr < 18) ? pr : pr - 18; }
            else { int r = pr - 36; py = 1 + (r >> 1); px = (r & 1) ? 17 : 0; }
            int ei = ((py * 4 + kc) * 18 + px) * 8;
            *(int4*)(R1 + ei) = z4;
            *(int4*)(R1 + 10368 + ei) = z4;
        }
    }
    __syncthreads();

    // ---------------- P1: conv1 (3->32 @32x32), relu+pool -> conv2 input -----
    {
        short8 b1h[2], b1l[2];
#pragma unroll
        for (int n = 0; n < 2; n++) {
            const short8* bp = (const short8*)(w1c2 + 16 * ((n * 16 + l15) * 4 + lg));
            b1h[n] = bp[0]; b1l[n] = bp[1];
        }
        int dyE[8], dxE[8], cbE[8];
#pragma unroll
        for (int e = 0; e < 8; e++) {
            int k = lg * 8 + e;
            if (k < 27) { int ci = k / 9, tp = k - ci * 9;
                          dyE[e] = tp / 3 - 1; dxE[e] = tp % 3 - 1; cbE[e] = ci << 10; }
            else { dyE[e] = -1000; dxE[e] = 0; cbE[e] = 0; }
        }
        float bia[2] = { b1c[l15], b1c[16 + l15] };
#pragma unroll 1
        for (int q = 0; q < 2; q++) {
            int m0 = 8 * w + 4 * q;
            f32x4 acc[4][2];
#pragma unroll
            for (int mi = 0; mi < 4; mi++)
#pragma unroll
                for (int n = 0; n < 2; n++) acc[mi][n] = (f32x4)0.f;
#pragma unroll
            for (int mi = 0; mi < 4; mi++) {
                int pos = 16 * (m0 + mi) + l15, py = pos >> 5, px = pos & 31;
                short8 ah, al;
#pragma unroll
                for (int e = 0; e < 8; e++) {
                    int yy = py + dyE[e], xv = px + dxE[e];
                    int idx = cbE[e] + (yy << 5) + xv;
                    bool ok = ((unsigned)yy < 32u) && ((unsigned)xv < 32u);
                    unsigned u = R2x[ok ? idx : 3072];
                    ah[e] = (short)(u >> 16);
                    al[e] = (short)(u & 0xFFFFu);
                }
#pragma unroll
                for (int n = 0; n < 2; n++) {
                    acc[mi][n] = MFMA(ah, b1h[n], acc[mi][n], 0, 0, 0);
                    acc[mi][n] = MFMA(ah, b1l[n], acc[mi][n], 0, 0, 0);
                    acc[mi][n] = MFMA(al, b1h[n], acc[mi][n], 0, 0, 0);
                }
            }
            int PY = 2 * w + q;
#pragma unroll
            for (int n = 0; n < 2; n++) {
                int o = n * 16 + l15;
#pragma unroll
                for (int h = 0; h < 2; h++)
#pragma unroll
                for (int jp = 0; jp < 2; jp++) {
                    float v00 = fmaxf(acc[h][n][2*jp]     + bia[n], 0.f);
                    float v01 = fmaxf(acc[h][n][2*jp + 1] + bia[n], 0.f);
                    float v10 = fmaxf(acc[h+2][n][2*jp]     + bia[n], 0.f);
                    float v11 = fmaxf(acc[h+2][n][2*jp + 1] + bia[n], 0.f);
                    float pm = fmaxf(fmaxf(v00, v01), fmaxf(v10, v11));
                    int PX = h * 8 + lg * 2 + jp;
                    unsigned short ph = rneb(pm), pl = rneb(pm - b2f(ph));
                    int ei = (((PY + 1) * 4 + (o >> 3)) * 18 + (PX + 1)) * 8 + (o & 7);
                    R1[ei] = ph; R1[10368 + ei] = pl;
                }
            }
        }
    }
    __syncthreads();

    // ---------------- P2: conv2 (32->64 @16x16), N-split waves + B prefetch ---
    {
        const int mh = w & 1, nn = w >> 1;
        f32x4 acc2[8];
#pragma unroll
        for (int mi = 0; mi < 8; mi++) acc2[mi] = (f32x4)0.f;
        const unsigned short* wb = w2c2 + ((size_t)(nn * 16 + l15) * 4 + lg) * 16;
        const int abase = (mh * 8) * 576 + lg * 144 + l15 * 8;
        short8 bhA, blA, bhB, blB;
#define LDB2(tp, BH, BL) { const short8* bp = (const short8*)(wb + (tp) * 4096); BH = bp[0]; BL = bp[1]; }
#define CMP2(tp, BH, BL) { int dy_ = (tp) / 3, dx_ = (tp) - 3 * dy_; \
        int roff_ = dy_ * 576 + dx_ * 8; \
        _Pragma("unroll") for (int mi = 0; mi < 8; mi++) { \
            int ea_ = abase + mi * 576 + roff_; \
            short8 ah_ = *(const short8*)(R1 + ea_); \
            short8 al_ = *(const short8*)(R1 + 10368 + ea_); \
            acc2[mi] = MFMA(ah_, BH, acc2[mi], 0, 0, 0); \
            acc2[mi] = MFMA(ah_, BL, acc2[mi], 0, 0, 0); \
            acc2[mi] = MFMA(al_, BH, acc2[mi], 0, 0, 0); } }
        LDB2(0, bhA, blA);
#pragma unroll 1
        for (int tp = 0; tp < 8; tp += 2) {
            LDB2(tp + 1, bhB, blB);
            CMP2(tp, bhA, blA);
            LDB2(tp + 2, bhA, blA);
            CMP2(tp + 1, bhB, blB);
        }
        CMP2(8, bhA, blA);
        __syncthreads();                            // conv2 reads of R1 done
        // epilogue: conv3-in halo zeros + relu+pool payload [py10][kc8][px11][e8]
        for (int hh = t; hh < 288; hh += 512) {     // 36 halo (py,px) x 8 kc
            int pr = hh >> 3, kc = hh & 7;
            int py, px;
            if (pr < 20) { py = (pr < 10) ? 0 : 9; px = (pr < 10) ? pr : pr - 10; }
            else { int r = pr - 20; py = 1 + (r >> 1); px = (r & 1) ? 9 : 0; }
            int ei = ((py * 8 + kc) * 11 + px) * 8;
            *(int4*)(R1 + ei) = z4;
            *(int4*)(R1 + 7040 + ei) = z4;
        }
        {
            int o = nn * 16 + l15;
            float bia = b2c[o];
#pragma unroll
            for (int mi2 = 0; mi2 < 4; mi2++) {
                int PY = mh * 4 + mi2;
#pragma unroll
                for (int jp = 0; jp < 2; jp++) {
                    float v00 = fmaxf(acc2[2*mi2][2*jp]     + bia, 0.f);
                    float v01 = fmaxf(acc2[2*mi2][2*jp + 1] + bia, 0.f);
                    float v10 = fmaxf(acc2[2*mi2+1][2*jp]     + bia, 0.f);
                    float v11 = fmaxf(acc2[2*mi2+1][2*jp + 1] + bia, 0.f);
                    float pm = fmaxf(fmaxf(v00, v01), fmaxf(v10, v11));
                    int PX = lg * 2 + jp;
                    unsigned short ph = rneb(pm), pl = rneb(pm - b2f(ph));
                    int ei = (((PY + 1) * 8 + (o >> 3)) * 11 + (PX + 1)) * 8 + (o & 7);
                    R1[ei] = ph; R1[7040 + ei] = pl;
                }
            }
        }
    }
    __syncthreads();

    // ---------------- P3: conv3 (64->128 @8x8), wave-per-nf + B prefetch ------
    {
        const int nf = w;
        f32x4 acc3[4];
#pragma unroll
        for (int mi = 0; mi < 4; mi++) acc3[mi] = (f32x4)0.f;
        const unsigned short* wb3 = w3c2 + ((size_t)(nf * 16 + l15) * 4 + lg) * 16;
        const int py0 = (l15 >> 3), px3 = l15 & 7;
        short8 bhA, blA, bhB, blB;
#define LDB3(ii, BH, BL) { const short8* bp = (const short8*)(wb3 + (ii) * 8192); BH = bp[0]; BL = bp[1]; }
#define CMP3(ii, BH, BL) { int tap_ = (ii) >> 1, s_ = (ii) & 1; \
        int dy_ = tap_ / 3, dx_ = tap_ - 3 * dy_; \
        int roff_ = dy_ * 704 + (s_ * 4 + lg) * 88 + dx_ * 8 + px3 * 8; \
        _Pragma("unroll") for (int mi = 0; mi < 4; mi++) { \
            int ea_ = (mi * 2 + py0) * 704 + roff_; \
            short8 ah_ = *(const short8*)(R1 + ea_); \
            short8 al_ = *(const short8*)(R1 + 7040 + ea_); \
            acc3[mi] = MFMA(ah_, BH, acc3[mi], 0, 0, 0); \
            acc3[mi] = MFMA(ah_, BL, acc3[mi], 0, 0, 0); \
            acc3[mi] = MFMA(al_, BH, acc3[mi], 0, 0, 0); } }
        LDB3(0, bhA, blA);
#pragma unroll 1
        for (int ii = 0; ii < 16; ii += 2) {
            LDB3(ii + 1, bhB, blB);
            CMP3(ii, bhA, blA);
            LDB3(ii + 2, bhA, blA);
            CMP3(ii + 1, bhB, blB);
        }
        LDB3(17, bhB, blB);
        CMP3(16, bhA, blA);
        CMP3(17, bhB, blB);
        // epilogue: relu + 2x2 maxpool + avg -> sFeat
        {
            int o = nf * 16 + l15;
            float bia = b3c[o];
            float featsum = 0.f;
#pragma unroll
            for (int mi = 0; mi < 4; mi++) {
                float sumv = 0.f;
#pragma unroll
                for (int jp = 0; jp < 2; jp++) {
                    float v0 = fmaxf(acc3[mi][2*jp]     + bia, 0.f);
                    float v1 = fmaxf(acc3[mi][2*jp + 1] + bia, 0.f);
                    float vm = fmaxf(v0, v1);
                    vm = fmaxf(vm, __shfl_xor(vm, 32, 64));   // py-pair
                    sumv += vm;
                }
                sumv += __shfl_xor(sumv, 16, 64);             // px halves
                featsum += sumv;
            }
            if (lane < 16) sFeat[nf * 16 + lane] = featsum * (1.0f / 16.0f);
        }
    }
    __syncthreads();

    // ---------------- P4: gate top-2 (all waves) + split expert MLPs ----------
    int i1 = 0, i2 = 0;
    float wk1 = 0.f, wk2 = 0.f;
    {
        float f0 = sFeat[lane], f1 = sFeat[64 + lane];
        float lgt[8];
#pragma unroll
        for (int e = 0; e < 8; e++) {
            float p = f0 * gw[lane * 8 + e] + f1 * gw[(64 + lane) * 8 + e];
#pragma unroll
            for (int s = 1; s < 64; s <<= 1) p += __shfl_xor(p, s, 64);
            lgt[e] = p + gb[e];
        }
        float v1m = -1e30f, v2m = -1e30f;
#pragma unroll
        for (int e = 0; e < 8; e++) {
            float le = lgt[e];
            if (le > v1m) { v2m = v1m; i2 = i1; v1m = le; i1 = e; }
            else if (le > v2m) { v2m = le; i2 = e; }
        }
        float ex = expf(v2m - v1m);
        wk1 = 1.f / (1.f + ex); wk2 = ex / (1.f + ex);
        // wave w: expert (w<4 ? i1 : i2), k-chunk (w&3)*32
        int e = (w < 4) ? i1 : i2;
        int k0 = (w & 3) * 32;
        const float* W1 = w1e + (size_t)e * 8192 + (size_t)k0 * 64;
        float hj = 0.f;
#pragma unroll 8
        for (int kk = 0; kk < 32; kk++) hj += sFeat[k0 + kk] * W1[kk * 64 + lane];
        sPart[w * 64 + lane] = hj;
    }
    __syncthreads();
    if (w < 2) {
        int e = (w == 0) ? i1 : i2;
        float wk = (w == 0) ? wk1 : wk2;
        float hj = b1e[e * 64 + lane]
                 + sPart[(w * 4 + 0) * 64 + lane] + sPart[(w * 4 + 1) * 64 + lane]
                 + sPart[(w * 4 + 2) * 64 + lane] + sPart[(w * 4 + 3) * 64 + lane];
        hj = fmaxf(hj, 0.f);
        const float* W2 = w2e + (size_t)e * 640 + lane * 10;
#pragma unroll
        for (int o = 0; o < 10; o++) {
            float po = hj * W2[o];
#pragma unroll
            for (int s = 1; s < 64; s <<= 1) po += __shfl_xor(po, s, 64);
            if (lane == 0) sOutB[w * 10 + o] = wk * (po + b2e[e * 10 + o]);
        }
    }
    __syncthreads();
    if (t < 10) out[(size_t)b * 10 + t] = sOutB[t] + sOutB[10 + t];
}

extern "C" void kernel_launch(void* const* d_in, const int* in_sizes, int n_in,
                              void* d_out, int out_size, void* d_ws, size_t ws_size,
                              hipStream_t stream)
{
    const float* x   = (const float*)d_in[0];
    const float* c1w = (const float*)d_in[1];
    const float* c1b = (const float*)d_in[2];
    const float* g1  = (const float*)d_in[3];
    const float* be1 = (const float*)d_in[4];
    const float* m1  = (const float*)d_in[5];
    const float* v1  = (const float*)d_in[6];
    const float* c2w = (const float*)d_in[7];
    const float* c2b = (const float*)d_in[8];
    const float* g2  = (const float*)d_in[9];
    const float* be2 = (const float*)d_in[10];
    const float* m2  = (const float*)d_in[11];
    const float* v2  = (const float*)d_in[12];
    const float* c3w = (const float*)d_in[13];
    const float* c3b = (const float*)d_in[14];
    const float* g3  = (const float*)d_in[15];
    const float* be3 = (const float*)d_in[16];
    const float* m3  = (const float*)d_in[17];
    const float* v3  = (const float*)d_in[18];
    const float* w1e = (const float*)d_in[19];
    const float* b1e = (const float*)d_in[20];
    const float* w2e = (const float*)d_in[21];
    const float* b2e = (const float*)d_in[22];
    const float* gw  = (const float*)d_in[23];
    const float* gb  = (const float*)d_in[24];

    float* ws = (float*)d_ws;
    unsigned short* w1c2 = (unsigned short*)(ws + W1C2_OFF);
    unsigned short* w2c2 = (unsigned short*)(ws + W2C2_OFF);
    unsigned short* w3c2 = (unsigned short*)(ws + W3C2_OFF);
    float* b1c = ws + B1_OFF;
    float* b2c = ws + B2_OFF;
    float* b3c = ws + B3_OFF;

    k_prep<<<729, 256, 0, stream>>>(c1w, c2w, c3w,
                                    c1b, g1, be1, m1, v1,
                                    c2b, g2, be2, m2, v2,
                                    c3b, g3, be3, m3, v3,
                                    w1c2, w2c2, w3c2, b1c, b2c, b3c);
    k_fused<<<4096, 512, 0, stream>>>(x, w1c2, w2c2, w3c2, b1c, b2c, b3c,
                                      w1e, b1e, w2e, b2e, gw, gb, (float*)d_out);
}